// Round 1
// baseline (897.918 us; speedup 1.0000x reference)
//
#include <hip/hip_runtime.h>
#include <hip/hip_bf16.h>
#include <cstdint>
#include <cstddef>

#define N_NODES 50000
#define DIM 512
#define N_EDGES 1600000

typedef __bf16 bf16;
typedef __bf16 bf16x8 __attribute__((ext_vector_type(8)));
typedef __bf16 bf16x4 __attribute__((ext_vector_type(4)));
typedef float floatx4 __attribute__((ext_vector_type(4)));

// ---------------- cast fp32 -> bf16 (4 elems / thread) ----------------
__global__ void cast_kernel(const float* __restrict__ in, bf16* __restrict__ out, int n4) {
    int i = blockIdx.x * blockDim.x + threadIdx.x;
    if (i >= n4) return;
    float4 v = reinterpret_cast<const float4*>(in)[i];
    bf16x4 o;
    o[0] = (bf16)v.x; o[1] = (bf16)v.y; o[2] = (bf16)v.z; o[3] = (bf16)v.w;
    reinterpret_cast<bf16x4*>(out)[i] = o;
}

// ---------------- CSR build ----------------
__global__ void hist_kernel(const int* __restrict__ rows, int* __restrict__ cnt, int E) {
    int i = blockIdx.x * blockDim.x + threadIdx.x;
    if (i < E) atomicAdd(&cnt[rows[i]], 1);
}

__global__ void scan_kernel(const int* __restrict__ cnt, int* __restrict__ row_start,
                            int* __restrict__ cursor) {
    __shared__ int sums[1024];
    const int t = threadIdx.x;
    const int CH = (N_NODES + 1023) / 1024;  // 49
    const int base = t * CH;
    int s = 0;
    for (int i = 0; i < CH; i++) {
        int idx = base + i;
        if (idx < N_NODES) s += cnt[idx];
    }
    sums[t] = s;
    __syncthreads();
    for (int off = 1; off < 1024; off <<= 1) {
        int v = (t >= off) ? sums[t - off] : 0;
        __syncthreads();
        sums[t] += v;
        __syncthreads();
    }
    int excl = (t == 0) ? 0 : sums[t - 1];
    for (int i = 0; i < CH; i++) {
        int idx = base + i;
        if (idx < N_NODES) {
            int c = cnt[idx];
            row_start[idx] = excl;
            cursor[idx] = excl;
            excl += c;
        }
    }
    if (t == 1023) row_start[N_NODES] = sums[1023];
}

__global__ void scatter_kernel(const int* __restrict__ rows, const int* __restrict__ cols,
                               const float* __restrict__ vals, int* __restrict__ cursor,
                               int* __restrict__ ecol, float* __restrict__ evalv, int E) {
    int i = blockIdx.x * blockDim.x + threadIdx.x;
    if (i >= E) return;
    int r = rows[i];
    int p = atomicAdd(&cursor[r], 1);
    ecol[p] = cols[i];
    evalv[p] = vals[i];
}

// ---------------- GEMM: y[M][512] = xb[M][512] @ Wb[512][512]^T (bf16 in, bf16 out) ----
__global__ __launch_bounds__(256) void gemm_kernel(const bf16* __restrict__ A,
                                                   const bf16* __restrict__ B,
                                                   bf16* __restrict__ C) {
    __shared__ bf16 lA[128 * 32];
    __shared__ bf16 lB[128 * 32];
    const int t = threadIdx.x;
    const int wave = t >> 6;
    const int lane = t & 63;
    const int rowBase = blockIdx.x * 128;
    const int colBase = blockIdx.y * 128;
    const int wm = (wave >> 1) * 64;
    const int wn = (wave & 1) * 64;
    floatx4 acc[4][4] = {};

    const int r_a = t >> 2;       // 0..63 (tile row, first half)
    const int kk = (t & 3) * 8;   // k offset within 32-chunk

    const int l15 = lane & 15;
    const int koff = (lane >> 4) * 8;

    for (int k0 = 0; k0 < DIM; k0 += 32) {
#pragma unroll
        for (int j = 0; j < 2; j++) {
            int row = rowBase + r_a + j * 64;
            if (row > N_NODES - 1) row = N_NODES - 1;  // clamp OOB loads (stores guarded)
            const bf16* g = A + (size_t)row * DIM + k0 + kk;
            bf16* l = lA + wave * 512 + j * 2048;  // wave-uniform base; HW adds lane*16B
            __builtin_amdgcn_global_load_lds(
                (const __attribute__((address_space(1))) void*)g,
                (__attribute__((address_space(3))) void*)l, 16, 0, 0);
        }
#pragma unroll
        for (int j = 0; j < 2; j++) {
            int row = colBase + r_a + j * 64;  // always < 512
            const bf16* g = B + (size_t)row * DIM + k0 + kk;
            bf16* l = lB + wave * 512 + j * 2048;
            __builtin_amdgcn_global_load_lds(
                (const __attribute__((address_space(1))) void*)g,
                (__attribute__((address_space(3))) void*)l, 16, 0, 0);
        }
        __syncthreads();
        bf16x8 af[4], bfr[4];
#pragma unroll
        for (int i = 0; i < 4; i++)
            af[i] = *reinterpret_cast<const bf16x8*>(lA + (wm + i * 16 + l15) * 32 + koff);
#pragma unroll
        for (int j = 0; j < 4; j++)
            bfr[j] = *reinterpret_cast<const bf16x8*>(lB + (wn + j * 16 + l15) * 32 + koff);
#pragma unroll
        for (int i = 0; i < 4; i++)
#pragma unroll
            for (int j = 0; j < 4; j++)
                acc[i][j] = __builtin_amdgcn_mfma_f32_16x16x32_bf16(af[i], bfr[j], acc[i][j], 0, 0, 0);
        __syncthreads();
    }
    // epilogue: D row = (lane>>4)*4+reg (m), col = lane&15 (n)
    const int rquad = (lane >> 4) * 4;
#pragma unroll
    for (int i = 0; i < 4; i++) {
#pragma unroll
        for (int reg = 0; reg < 4; reg++) {
            int gr = rowBase + wm + i * 16 + rquad + reg;
            if (gr >= N_NODES) continue;
#pragma unroll
            for (int j = 0; j < 4; j++) {
                int gc = colBase + wn + j * 16 + l15;
                C[(size_t)gr * DIM + gc] = (bf16)acc[i][j][reg];
            }
        }
    }
}

// ---------------- SpMM: one wave per row, lane owns 8 dims ----------------
__device__ __forceinline__ float blo(uint32_t w) { return __uint_as_float(w << 16); }
__device__ __forceinline__ float bhi(uint32_t w) { return __uint_as_float(w & 0xffff0000u); }

__global__ __launch_bounds__(256) void spmm_kernel(const int* __restrict__ row_start,
                                                   const int* __restrict__ ecol,
                                                   const float* __restrict__ evalv,
                                                   const bf16* __restrict__ y,
                                                   float* __restrict__ y2) {
    const int wave = threadIdx.x >> 6;
    const int lane = threadIdx.x & 63;
    const int r = blockIdx.x * 4 + wave;  // grid = 12500 exactly -> r < 50000
    const int s = row_start[r];
    const int e = row_start[r + 1];
    float acc[8] = {0.f, 0.f, 0.f, 0.f, 0.f, 0.f, 0.f, 0.f};
    const uint32_t* yb = reinterpret_cast<const uint32_t*>(y);

    int i = s;
    for (; i + 1 < e; i += 2) {
        int c0 = ecol[i], c1 = ecol[i + 1];
        float v0 = evalv[i], v1 = evalv[i + 1];
        uint4 w0 = *reinterpret_cast<const uint4*>(yb + (size_t)c0 * 256 + lane * 4);
        uint4 w1 = *reinterpret_cast<const uint4*>(yb + (size_t)c1 * 256 + lane * 4);
        acc[0] += v0 * blo(w0.x); acc[1] += v0 * bhi(w0.x);
        acc[2] += v0 * blo(w0.y); acc[3] += v0 * bhi(w0.y);
        acc[4] += v0 * blo(w0.z); acc[5] += v0 * bhi(w0.z);
        acc[6] += v0 * blo(w0.w); acc[7] += v0 * bhi(w0.w);
        acc[0] += v1 * blo(w1.x); acc[1] += v1 * bhi(w1.x);
        acc[2] += v1 * blo(w1.y); acc[3] += v1 * bhi(w1.y);
        acc[4] += v1 * blo(w1.z); acc[5] += v1 * bhi(w1.z);
        acc[6] += v1 * blo(w1.w); acc[7] += v1 * bhi(w1.w);
    }
    if (i < e) {
        int c0 = ecol[i];
        float v0 = evalv[i];
        uint4 w0 = *reinterpret_cast<const uint4*>(yb + (size_t)c0 * 256 + lane * 4);
        acc[0] += v0 * blo(w0.x); acc[1] += v0 * bhi(w0.x);
        acc[2] += v0 * blo(w0.y); acc[3] += v0 * bhi(w0.y);
        acc[4] += v0 * blo(w0.z); acc[5] += v0 * bhi(w0.z);
        acc[6] += v0 * blo(w0.w); acc[7] += v0 * bhi(w0.w);
    }
    float4* out = reinterpret_cast<float4*>(y2 + (size_t)r * DIM + lane * 8);
    out[0] = make_float4(acc[0], acc[1], acc[2], acc[3]);
    out[1] = make_float4(acc[4], acc[5], acc[6], acc[7]);
}

// ---------------- reduction: colsum[512] + total sum of squares ----------------
__global__ __launch_bounds__(256) void reduce_kernel(const float* __restrict__ y2,
                                                     float* __restrict__ colsum,
                                                     float* __restrict__ totsq) {
    const int t = threadIdx.x;
    const int d2 = t * 2;
    float c0 = 0.f, c1 = 0.f, sq = 0.f;
    for (int r = blockIdx.x; r < N_NODES; r += gridDim.x) {
        float2 v = *reinterpret_cast<const float2*>(y2 + (size_t)r * DIM + d2);
        c0 += v.x; c1 += v.y;
        sq += v.x * v.x + v.y * v.y;
    }
    atomicAdd(&colsum[d2], c0);
    atomicAdd(&colsum[d2 + 1], c1);
    __shared__ float ssq[256];
    ssq[t] = sq;
    __syncthreads();
    for (int off = 128; off > 0; off >>= 1) {
        if (t < off) ssq[t] += ssq[t + off];
        __syncthreads();
    }
    if (t == 0) atomicAdd(totsq, ssq[0]);
}

__global__ void scalar_kernel(const float* __restrict__ colsum, const float* __restrict__ totsq,
                              const float* __restrict__ scale, float* __restrict__ sfac) {
    __shared__ float sm[512];
    const int t = threadIdx.x;
    float mu = colsum[t] * (1.0f / N_NODES);
    sm[t] = mu * mu;
    __syncthreads();
    for (int off = 256; off > 0; off >>= 1) {
        if (t < off) sm[t] += sm[t + off];
        __syncthreads();
    }
    if (t == 0) {
        // sum over all y_t^2 = totsq - N * sum(mu^2);  y_norm = rsqrt(that / N)
        float var = totsq[0] * (1.0f / N_NODES) - sm[0];
        sfac[0] = rsqrtf(var) * (1.0f + scale[0]) * sqrtf((float)DIM);
    }
}

// ---------------- final: out = relu((y2 - mu) * s) + x  (in place on d_out) ----------------
__global__ void final_kernel(float* __restrict__ y2, const float* __restrict__ x,
                             const float* __restrict__ colsum, const float* __restrict__ sfac,
                             int n4) {
    int i = blockIdx.x * blockDim.x + threadIdx.x;
    if (i >= n4) return;
    const float invN = 1.0f / N_NODES;
    float4 v = reinterpret_cast<float4*>(y2)[i];
    float4 xv = reinterpret_cast<const float4*>(x)[i];
    float4 mu = reinterpret_cast<const float4*>(colsum)[i & 127];
    float s = sfac[0];
    v.x = fmaxf((v.x - mu.x * invN) * s, 0.0f) + xv.x;
    v.y = fmaxf((v.y - mu.y * invN) * s, 0.0f) + xv.y;
    v.z = fmaxf((v.z - mu.z * invN) * s, 0.0f) + xv.z;
    v.w = fmaxf((v.w - mu.w * invN) * s, 0.0f) + xv.w;
    reinterpret_cast<float4*>(y2)[i] = v;
}

extern "C" void kernel_launch(void* const* d_in, const int* in_sizes, int n_in,
                              void* d_out, int out_size, void* d_ws, size_t ws_size,
                              hipStream_t stream) {
    const float* x        = (const float*)d_in[0];
    const int*   adj_rows = (const int*)d_in[1];
    const int*   adj_cols = (const int*)d_in[2];
    const float* adj_vals = (const float*)d_in[3];
    const float* weight   = (const float*)d_in[4];
    const float* scale    = (const float*)d_in[5];
    float* out = (float*)d_out;  // doubles as y2 buffer

    char* ws = (char*)d_ws;
    size_t off = 0;
    auto alloc = [&](size_t b) {
        char* p = ws + off;
        off += (b + 255) & ~(size_t)255;
        return p;
    };
    bf16*  xb        = (bf16*)alloc((size_t)N_NODES * DIM * 2);   // 51.2 MB
    bf16*  Wb        = (bf16*)alloc((size_t)DIM * DIM * 2);       // 0.5 MB
    bf16*  y         = (bf16*)alloc((size_t)N_NODES * DIM * 2);   // 51.2 MB
    int*   cnt       = (int*)alloc((size_t)N_NODES * 4);
    int*   row_start = (int*)alloc((size_t)(N_NODES + 1) * 4);
    int*   cursor    = (int*)alloc((size_t)N_NODES * 4);
    int*   ecol      = (int*)alloc((size_t)N_EDGES * 4);          // 6.4 MB
    float* evalv     = (float*)alloc((size_t)N_EDGES * 4);        // 6.4 MB
    float* colsum    = (float*)alloc(512 * 4);
    float* totsq     = (float*)alloc(4);
    float* sfac      = (float*)alloc(4);
    (void)ws_size; (void)in_sizes; (void)n_in; (void)out_size;

    hipMemsetAsync(cnt, 0, (size_t)N_NODES * 4, stream);
    hipMemsetAsync(colsum, 0, 512 * 4, stream);
    hipMemsetAsync(totsq, 0, 4, stream);

    const int n4x = N_NODES * DIM / 4;  // 6,400,000
    const int n4w = DIM * DIM / 4;      // 65,536
    cast_kernel<<<(n4x + 255) / 256, 256, 0, stream>>>(x, xb, n4x);
    cast_kernel<<<(n4w + 255) / 256, 256, 0, stream>>>(weight, Wb, n4w);

    hist_kernel<<<(N_EDGES + 255) / 256, 256, 0, stream>>>(adj_rows, cnt, N_EDGES);
    scan_kernel<<<1, 1024, 0, stream>>>(cnt, row_start, cursor);
    scatter_kernel<<<(N_EDGES + 255) / 256, 256, 0, stream>>>(adj_rows, adj_cols, adj_vals,
                                                              cursor, ecol, evalv, N_EDGES);

    gemm_kernel<<<dim3((N_NODES + 127) / 128, DIM / 128), 256, 0, stream>>>(xb, Wb, y);

    spmm_kernel<<<N_NODES / 4, 256, 0, stream>>>(row_start, ecol, evalv, y, out);

    reduce_kernel<<<256, 256, 0, stream>>>(out, colsum, totsq);
    scalar_kernel<<<1, 512, 0, stream>>>(colsum, totsq, scale, sfac);
    final_kernel<<<(n4x + 255) / 256, 256, 0, stream>>>(out, x, colsum, sfac, n4x);
}

// Round 2
// 732.564 us; speedup vs baseline: 1.2257x; 1.2257x over previous
//
#include <hip/hip_runtime.h>
#include <hip/hip_bf16.h>
#include <cstdint>
#include <cstddef>

#define N_NODES 50000
#define DIM 512
#define N_EDGES 1600000
#define NT 25           // column tiles of 2048 nodes (2 MB of bf16 y per tile)
#define NB (N_NODES * NT)

typedef __bf16 bf16;
typedef __bf16 bf16x8 __attribute__((ext_vector_type(8)));
typedef __bf16 bf16x4 __attribute__((ext_vector_type(4)));
typedef float floatx4 __attribute__((ext_vector_type(4)));

// ---------------- cast fp32 -> bf16 (4 elems / thread) ----------------
__global__ void cast_kernel(const float* __restrict__ in, bf16* __restrict__ out, int n4) {
    int i = blockIdx.x * blockDim.x + threadIdx.x;
    if (i >= n4) return;
    float4 v = reinterpret_cast<const float4*>(in)[i];
    bf16x4 o;
    o[0] = (bf16)v.x; o[1] = (bf16)v.y; o[2] = (bf16)v.z; o[3] = (bf16)v.w;
    reinterpret_cast<bf16x4*>(out)[i] = o;
}

// ---------------- bucketed CSR build: key = row*NT + (col>>11) ----------------
__global__ void hist_kernel(const int* __restrict__ rows, const int* __restrict__ cols,
                            int* __restrict__ cnt, int E) {
    int i = blockIdx.x * blockDim.x + threadIdx.x;
    if (i < E) {
        int key = rows[i] * NT + (cols[i] >> 11);
        atomicAdd(&cnt[key], 1);
    }
}

// hierarchical scan over NB buckets
__global__ __launch_bounds__(1024) void scanA_kernel(const int* __restrict__ cnt,
                                                     int* __restrict__ row_start,
                                                     int* __restrict__ blksum, int n) {
    __shared__ int s[1024];
    const int t = threadIdx.x;
    int i = blockIdx.x * 1024 + t;
    int v = (i < n) ? cnt[i] : 0;
    s[t] = v;
    __syncthreads();
    for (int off = 1; off < 1024; off <<= 1) {
        int u = (t >= off) ? s[t - off] : 0;
        __syncthreads();
        s[t] += u;
        __syncthreads();
    }
    if (i < n) row_start[i] = s[t] - v;  // exclusive within block
    if (t == 1023) blksum[blockIdx.x] = s[1023];
}

__global__ __launch_bounds__(1024) void scanB_kernel(const int* __restrict__ blksum,
                                                     int* __restrict__ blkoff, int nb) {
    __shared__ int s[1024];
    const int t = threadIdx.x;
    const int base = t * 2;
    int a = (base < nb) ? blksum[base] : 0;
    int b = (base + 1 < nb) ? blksum[base + 1] : 0;
    s[t] = a + b;
    __syncthreads();
    for (int off = 1; off < 1024; off <<= 1) {
        int u = (t >= off) ? s[t - off] : 0;
        __syncthreads();
        s[t] += u;
        __syncthreads();
    }
    int excl = (t == 0) ? 0 : s[t - 1];
    if (base < nb) blkoff[base] = excl;
    if (base + 1 < nb) blkoff[base + 1] = excl + a;
}

__global__ __launch_bounds__(1024) void scanC_kernel(int* __restrict__ row_start,
                                                     const int* __restrict__ blkoff,
                                                     int* __restrict__ cursor, int n) {
    int i = blockIdx.x * 1024 + threadIdx.x;
    if (i >= n) return;
    int v = row_start[i] + blkoff[i >> 10];
    row_start[i] = v;
    cursor[i] = v;
    if (i == n - 1) row_start[n] = N_EDGES;
}

__global__ void scatter_kernel(const int* __restrict__ rows, const int* __restrict__ cols,
                               const float* __restrict__ vals, int* __restrict__ cursor,
                               int2* __restrict__ ecv, int E) {
    int i = blockIdx.x * blockDim.x + threadIdx.x;
    if (i >= E) return;
    int c = cols[i];
    int key = rows[i] * NT + (c >> 11);
    int p = atomicAdd(&cursor[key], 1);
    ecv[p] = make_int2(c, __float_as_int(vals[i]));
}

// ---------------- GEMM: y[M][512] = xb[M][512] @ Wb[512][512]^T (bf16 in, bf16 out) ----
__global__ __launch_bounds__(256) void gemm_kernel(const bf16* __restrict__ A,
                                                   const bf16* __restrict__ B,
                                                   bf16* __restrict__ C) {
    __shared__ bf16 lA[128 * 32];
    __shared__ bf16 lB[128 * 32];
    const int t = threadIdx.x;
    const int wave = t >> 6;
    const int lane = t & 63;
    const int rowBase = blockIdx.x * 128;
    const int colBase = blockIdx.y * 128;
    const int wm = (wave >> 1) * 64;
    const int wn = (wave & 1) * 64;
    floatx4 acc[4][4] = {};

    const int r_a = t >> 2;       // 0..63 (tile row, first half)
    const int kk = (t & 3) * 8;   // k offset within 32-chunk

    const int l15 = lane & 15;
    const int koff = (lane >> 4) * 8;

    for (int k0 = 0; k0 < DIM; k0 += 32) {
#pragma unroll
        for (int j = 0; j < 2; j++) {
            int row = rowBase + r_a + j * 64;
            if (row > N_NODES - 1) row = N_NODES - 1;  // clamp OOB loads (stores guarded)
            const bf16* g = A + (size_t)row * DIM + k0 + kk;
            bf16* l = lA + wave * 512 + j * 2048;  // wave-uniform base; HW adds lane*16B
            __builtin_amdgcn_global_load_lds(
                (const __attribute__((address_space(1))) void*)g,
                (__attribute__((address_space(3))) void*)l, 16, 0, 0);
        }
#pragma unroll
        for (int j = 0; j < 2; j++) {
            int row = colBase + r_a + j * 64;  // always < 512
            const bf16* g = B + (size_t)row * DIM + k0 + kk;
            bf16* l = lB + wave * 512 + j * 2048;
            __builtin_amdgcn_global_load_lds(
                (const __attribute__((address_space(1))) void*)g,
                (__attribute__((address_space(3))) void*)l, 16, 0, 0);
        }
        __syncthreads();
        bf16x8 af[4], bfr[4];
#pragma unroll
        for (int i = 0; i < 4; i++)
            af[i] = *reinterpret_cast<const bf16x8*>(lA + (wm + i * 16 + l15) * 32 + koff);
#pragma unroll
        for (int j = 0; j < 4; j++)
            bfr[j] = *reinterpret_cast<const bf16x8*>(lB + (wn + j * 16 + l15) * 32 + koff);
#pragma unroll
        for (int i = 0; i < 4; i++)
#pragma unroll
            for (int j = 0; j < 4; j++)
                acc[i][j] = __builtin_amdgcn_mfma_f32_16x16x32_bf16(af[i], bfr[j], acc[i][j], 0, 0, 0);
        __syncthreads();
    }
    // epilogue: D row = (lane>>4)*4+reg (m), col = lane&15 (n)
    const int rquad = (lane >> 4) * 4;
#pragma unroll
    for (int i = 0; i < 4; i++) {
#pragma unroll
        for (int reg = 0; reg < 4; reg++) {
            int gr = rowBase + wm + i * 16 + rquad + reg;
            if (gr >= N_NODES) continue;
#pragma unroll
            for (int j = 0; j < 4; j++) {
                int gc = colBase + wn + j * 16 + l15;
                C[(size_t)gr * DIM + gc] = (bf16)acc[i][j][reg];
            }
        }
    }
}

// ---------------- SpMM: one wave per row, lane owns 8 dims, edges tile-sorted ----------------
__device__ __forceinline__ float blo(uint32_t w) { return __uint_as_float(w << 16); }
__device__ __forceinline__ float bhi(uint32_t w) { return __uint_as_float(w & 0xffff0000u); }

__device__ __forceinline__ void fmac8(float* acc, float v, const uint4& w) {
    acc[0] += v * blo(w.x); acc[1] += v * bhi(w.x);
    acc[2] += v * blo(w.y); acc[3] += v * bhi(w.y);
    acc[4] += v * blo(w.z); acc[5] += v * bhi(w.z);
    acc[6] += v * blo(w.w); acc[7] += v * bhi(w.w);
}

__global__ __launch_bounds__(256) void spmm_kernel(const int* __restrict__ row_start,
                                                   const int2* __restrict__ ecv,
                                                   const bf16* __restrict__ y,
                                                   float* __restrict__ y2) {
    const int wave = threadIdx.x >> 6;
    const int lane = threadIdx.x & 63;
    const int r = blockIdx.x * 4 + wave;  // grid = 12500 exactly -> r < 50000
    const int s = row_start[r * NT];
    const int e = row_start[(r + 1) * NT];
    float acc[8] = {0.f, 0.f, 0.f, 0.f, 0.f, 0.f, 0.f, 0.f};
    const uint32_t* yb = reinterpret_cast<const uint32_t*>(y);

    int i = s;
    for (; i + 3 < e; i += 4) {
        int2 e0 = ecv[i], e1 = ecv[i + 1], e2 = ecv[i + 2], e3 = ecv[i + 3];
        uint4 w0 = *reinterpret_cast<const uint4*>(yb + (size_t)e0.x * 256 + lane * 4);
        uint4 w1 = *reinterpret_cast<const uint4*>(yb + (size_t)e1.x * 256 + lane * 4);
        uint4 w2 = *reinterpret_cast<const uint4*>(yb + (size_t)e2.x * 256 + lane * 4);
        uint4 w3 = *reinterpret_cast<const uint4*>(yb + (size_t)e3.x * 256 + lane * 4);
        fmac8(acc, __int_as_float(e0.y), w0);
        fmac8(acc, __int_as_float(e1.y), w1);
        fmac8(acc, __int_as_float(e2.y), w2);
        fmac8(acc, __int_as_float(e3.y), w3);
    }
    for (; i < e; i++) {
        int2 e0 = ecv[i];
        uint4 w0 = *reinterpret_cast<const uint4*>(yb + (size_t)e0.x * 256 + lane * 4);
        fmac8(acc, __int_as_float(e0.y), w0);
    }
    float4* out = reinterpret_cast<float4*>(y2 + (size_t)r * DIM + lane * 8);
    out[0] = make_float4(acc[0], acc[1], acc[2], acc[3]);
    out[1] = make_float4(acc[4], acc[5], acc[6], acc[7]);
}

// ---------------- reduction: colsum[512] + total sum of squares ----------------
__global__ __launch_bounds__(256) void reduce_kernel(const float* __restrict__ y2,
                                                     float* __restrict__ colsum,
                                                     float* __restrict__ totsq) {
    const int t = threadIdx.x;
    const int d2 = t * 2;
    float c0 = 0.f, c1 = 0.f, sq = 0.f;
    for (int r = blockIdx.x; r < N_NODES; r += gridDim.x) {
        float2 v = *reinterpret_cast<const float2*>(y2 + (size_t)r * DIM + d2);
        c0 += v.x; c1 += v.y;
        sq += v.x * v.x + v.y * v.y;
    }
    atomicAdd(&colsum[d2], c0);
    atomicAdd(&colsum[d2 + 1], c1);
    __shared__ float ssq[256];
    ssq[t] = sq;
    __syncthreads();
    for (int off = 128; off > 0; off >>= 1) {
        if (t < off) ssq[t] += ssq[t + off];
        __syncthreads();
    }
    if (t == 0) atomicAdd(totsq, ssq[0]);
}

__global__ void scalar_kernel(const float* __restrict__ colsum, const float* __restrict__ totsq,
                              const float* __restrict__ scale, float* __restrict__ sfac) {
    __shared__ float sm[512];
    const int t = threadIdx.x;
    float mu = colsum[t] * (1.0f / N_NODES);
    sm[t] = mu * mu;
    __syncthreads();
    for (int off = 256; off > 0; off >>= 1) {
        if (t < off) sm[t] += sm[t + off];
        __syncthreads();
    }
    if (t == 0) {
        float var = totsq[0] * (1.0f / N_NODES) - sm[0];
        sfac[0] = rsqrtf(var) * (1.0f + scale[0]) * sqrtf((float)DIM);
    }
}

// ---------------- final: out = relu((y2 - mu) * s) + x  (in place on d_out) ----------------
__global__ void final_kernel(float* __restrict__ y2, const float* __restrict__ x,
                             const float* __restrict__ colsum, const float* __restrict__ sfac,
                             int n4) {
    int i = blockIdx.x * blockDim.x + threadIdx.x;
    if (i >= n4) return;
    const float invN = 1.0f / N_NODES;
    float4 v = reinterpret_cast<float4*>(y2)[i];
    float4 xv = reinterpret_cast<const float4*>(x)[i];
    float4 mu = reinterpret_cast<const float4*>(colsum)[i & 127];
    float s = sfac[0];
    v.x = fmaxf((v.x - mu.x * invN) * s, 0.0f) + xv.x;
    v.y = fmaxf((v.y - mu.y * invN) * s, 0.0f) + xv.y;
    v.z = fmaxf((v.z - mu.z * invN) * s, 0.0f) + xv.z;
    v.w = fmaxf((v.w - mu.w * invN) * s, 0.0f) + xv.w;
    reinterpret_cast<float4*>(y2)[i] = v;
}

extern "C" void kernel_launch(void* const* d_in, const int* in_sizes, int n_in,
                              void* d_out, int out_size, void* d_ws, size_t ws_size,
                              hipStream_t stream) {
    const float* x        = (const float*)d_in[0];
    const int*   adj_rows = (const int*)d_in[1];
    const int*   adj_cols = (const int*)d_in[2];
    const float* adj_vals = (const float*)d_in[3];
    const float* weight   = (const float*)d_in[4];
    const float* scale    = (const float*)d_in[5];
    float* out = (float*)d_out;  // doubles as y2 buffer

    char* ws = (char*)d_ws;
    size_t off = 0;
    auto alloc = [&](size_t b) {
        char* p = ws + off;
        off += (b + 255) & ~(size_t)255;
        return p;
    };
    const int nblk = (NB + 1023) / 1024;  // 1221
    bf16*  xb        = (bf16*)alloc((size_t)N_NODES * DIM * 2);   // 51.2 MB
    int2*  ecv       = (int2*)xb;  // ALIAS: gemm (reader of xb) completes before scatter writes
    bf16*  Wb        = (bf16*)alloc((size_t)DIM * DIM * 2);       // 0.5 MB
    bf16*  y         = (bf16*)alloc((size_t)N_NODES * DIM * 2);   // 51.2 MB
    int*   cnt       = (int*)alloc((size_t)NB * 4);               // 5 MB
    int*   cursor    = cnt;        // ALIAS: cnt dead after scanA; cursor born in scanC
    int*   row_start = (int*)alloc((size_t)(NB + 1) * 4);         // 5 MB
    int*   blksum    = (int*)alloc((size_t)nblk * 4);
    int*   blkoff    = (int*)alloc((size_t)nblk * 4);
    float* colsum    = (float*)alloc(512 * 4);
    float* totsq     = (float*)alloc(4);
    float* sfac      = (float*)alloc(4);
    (void)ws_size; (void)in_sizes; (void)n_in; (void)out_size;

    hipMemsetAsync(cnt, 0, (size_t)NB * 4, stream);
    hipMemsetAsync(colsum, 0, 512 * 4, stream);
    hipMemsetAsync(totsq, 0, 4, stream);

    const int n4x = N_NODES * DIM / 4;  // 6,400,000
    const int n4w = DIM * DIM / 4;      // 65,536
    cast_kernel<<<(n4x + 255) / 256, 256, 0, stream>>>(x, xb, n4x);
    cast_kernel<<<(n4w + 255) / 256, 256, 0, stream>>>(weight, Wb, n4w);

    // GEMM first: frees xb so ecv can alias it
    gemm_kernel<<<dim3((N_NODES + 127) / 128, DIM / 128), 256, 0, stream>>>(xb, Wb, y);

    hist_kernel<<<(N_EDGES + 255) / 256, 256, 0, stream>>>(adj_rows, adj_cols, cnt, N_EDGES);
    scanA_kernel<<<nblk, 1024, 0, stream>>>(cnt, row_start, blksum, NB);
    scanB_kernel<<<1, 1024, 0, stream>>>(blksum, blkoff, nblk);
    scanC_kernel<<<nblk, 1024, 0, stream>>>(row_start, blkoff, cursor, NB);
    scatter_kernel<<<(N_EDGES + 255) / 256, 256, 0, stream>>>(adj_rows, adj_cols, adj_vals,
                                                              cursor, ecv, N_EDGES);

    spmm_kernel<<<N_NODES / 4, 256, 0, stream>>>(row_start, ecv, y, out);

    reduce_kernel<<<256, 256, 0, stream>>>(out, colsum, totsq);
    scalar_kernel<<<1, 512, 0, stream>>>(colsum, totsq, scale, sfac);
    final_kernel<<<(n4x + 255) / 256, 256, 0, stream>>>(out, x, colsum, sfac, n4x);
}